// Round 12
// baseline (92.715 us; speedup 1.0000x reference)
//
#include <hip/hip_runtime.h>

#define Bb 4
#define Cc 256
#define Ss 256
#define Hh 128
#define Ww 128
#define Jj 8
#define HWp 16384   // H*W
#define BN_EPS 1e-5f

// ---------------- workspace byte offsets ----------------
#define WS_PS   0          // 1024 f32 partial sums; REUSED after k_build as T[256] float4
#define WS_PQ   4096       // 1024 f32 partial sumsq
#define WS_MU   10240      // mu       4*8*256 f32 (32768 B)
#define WS_LAB  43008      // labels   4*128*128 u8 (65536 B)
#define WS_WTG  108544     // Wt_gamma 2304*256 f32 (2359296 B)
#define WS_WTB  2467840    // Wt_beta  2304*256 f32
#define WS_VT   4827136    // Vt [cc8][b4] fp16 slices of 12288 B = 393216 B

// V-row (fp16): [g 32ch*2B | e 32ch*2B | 16B pad] = 144 B. j*144B = j*36 dwords ->
// start banks {0,4,...,28}: disjoint 4-bank spans for j=0..7; j=8 aliases j=0 (2-way, free).
#define VROW 144
#define SLICE_B 12288      // 81*144 = 11664, padded to 12*1024 for width-16 staging
#define SLICE_H 6144       // halves

typedef _Float16 h8 __attribute__((ext_vector_type(8)));

// ---- K1 (merged prep): bn-partial | labels | mu | transpose, split by blockIdx ----
__global__ void k_prep(const float* __restrict__ fp, const float* __restrict__ sg,
                       const float* __restrict__ style, const int* __restrict__ mask,
                       const float* __restrict__ Wmu, const float* __restrict__ bmu,
                       const float* __restrict__ Wg, const float* __restrict__ Wb,
                       float* __restrict__ ws_f, unsigned char* __restrict__ labout,
                       float* __restrict__ muout,
                       float* __restrict__ wtg, float* __restrict__ wtb) {
    __shared__ float smem[1056];           // max: transpose tile 32*33
    const int t = threadIdx.x;
    const int blk = blockIdx.x;
    if (blk < 1024) {
        // per-(c,b) partial sums for BN stats; wave shfl-reduce, 1 barrier only
        const int c = blk >> 2, b = blk & 3;
        const float4* s4 = (const float4*)(fp + (size_t)(b * Cc + c) * HWp);
        float sum = 0.f, sq = 0.f;
        #pragma unroll
        for (int k = 0; k < 16; ++k) {
            float4 v = s4[t + k * 256];
            sum += v.x + v.y + v.z + v.w;
            sq  += v.x * v.x + v.y * v.y + v.z * v.z + v.w * v.w;
        }
        #pragma unroll
        for (int off = 32; off > 0; off >>= 1) {
            sum += __shfl_xor(sum, off);
            sq  += __shfl_xor(sq,  off);
        }
        const int lane = t & 63, wv = t >> 6;
        if (lane == 0) { smem[wv] = sum; smem[4 + wv] = sq; }
        __syncthreads();
        if (t == 0) {
            ws_f[blk]        = (smem[0] + smem[1]) + (smem[2] + smem[3]);
            ws_f[1024 + blk] = (smem[4] + smem[5]) + (smem[6] + smem[7]);
        }
    } else if (blk < 1280) {
        // labels from one-hot sg
        const int i = (blk - 1024) * 256 + t;
        const int b = i >> 14, p = i & (HWp - 1);
        const float* base = sg + (size_t)b * Jj * HWp + p;
        int l = 0;
        #pragma unroll
        for (int j = 0; j < Jj; ++j)
            if (base[(size_t)j * HWp] > 0.5f) l = j;
        labout[i] = (unsigned char)l;
    } else if (blk < 1312) {
        // per-(b,j) style FC + ReLU -> mu
        const int lb = blk - 1280;
        const int b = lb >> 3, j = lb & 7;
        const int sel = (mask[b * Jj + j] == 1) ? j : Jj;
        float* code = smem;
        code[t] = style[(size_t)(b * (Jj + 1) + sel) * Ss + t];
        __syncthreads();
        const float4* wrow = (const float4*)(Wmu + (size_t)(j * Ss + t) * Ss);
        const float4* c4 = (const float4*)code;
        float acc = bmu[j * Ss + t];
        #pragma unroll 8
        for (int s4i = 0; s4i < Ss / 4; ++s4i) {
            float4 w = wrow[s4i]; float4 cv = c4[s4i];
            acc += w.x * cv.x + w.y * cv.y + w.z * cv.z + w.w * cv.w;
        }
        muout[(size_t)lb * Ss + t] = fmaxf(acc, 0.f);
    } else {
        // LDS-tiled transpose [256][2304] -> [2304][256]
        const int local = blk - 1312;            // 0..1151
        const int z = local / 576;
        const int rem = local % 576;
        const int k0 = (rem % 72) * 32;
        const int r0 = (rem / 72) * 32;
        const float* in = z ? Wb : Wg;
        float* outp = z ? wtb : wtg;
        float (*tile)[33] = (float(*)[33])smem;
        const int tx = t & 31, ty = t >> 5;
        #pragma unroll
        for (int i2 = 0; i2 < 4; ++i2)
            tile[ty + 8 * i2][tx] = in[(size_t)(r0 + ty + 8 * i2) * 2304 + k0 + tx];
        __syncthreads();
        #pragma unroll
        for (int i2 = 0; i2 < 4; ++i2)
            outp[(size_t)(k0 + ty + 8 * i2) * 256 + r0 + tx] = tile[tx][ty + 8 * i2];
    }
}

// ---- K2: blk 0 = BN finalize -> T table; blks 1..72 = Vt build, 1024 threads ----
// s-dimension split across 4 wave-groups (sq = t>>8, SGPR-forced); mu[b][j][s] is
// wave-uniform -> scalar (s_load) path, NO LDS in the MAC loop. Partials combined
// via a padded-LDS reduce. Vt layout unchanged: fp16 [tap*9+j][g 32 | e 32]; row 8 = 0.
__global__ void k_build(const float* __restrict__ bn_g, const float* __restrict__ bn_b,
                        const float* __restrict__ bgam, const float* __restrict__ bbet,
                        const float* __restrict__ wtg, const float* __restrict__ wtb,
                        const float* __restrict__ mu, float* __restrict__ ws_f,
                        _Float16* __restrict__ vt) {
    const int t = threadIdx.x;
    if (blockIdx.x == 0) {
        if (t < 256) {
            // T[c] = (scale, shift, 1 + b_gamma, b_beta); overwrites PS region (safe:
            // each thread reads exactly floats [4t,4t+4) of PS before writing them)
            float s = 0.f, q = 0.f;
            #pragma unroll
            for (int b = 0; b < 4; ++b) { s += ws_f[t * 4 + b]; q += ws_f[1024 + t * 4 + b]; }
            float mean = s * (1.f / 65536.f);
            float var  = q * (1.f / 65536.f) - mean * mean;
            float sc = bn_g[t] * rsqrtf(var + BN_EPS);
            float sh = bn_b[t] - mean * sc;
            ((float4*)ws_f)[t] = make_float4(sc, sh, 1.f + bgam[t], bbet[t]);
        }
        return;
    }
    const int lb = blockIdx.x - 1;          // 0..71
    const int z = lb / 36;
    const int rem = lb % 36;
    const int tap = rem % 9, b = rem / 9;
    const float* Wt = z ? wtb : wtg;
    const int c = t & 255;
    const int sq = __builtin_amdgcn_readfirstlane(t >> 8);   // s-quarter, SGPR
    const float* mub = mu + (size_t)b * Jj * Ss;             // wave-uniform reads
    float ag[8] = {0,0,0,0,0,0,0,0};
    const float* wp = Wt + (size_t)tap * 256 + c;
    #pragma unroll 16
    for (int si = 0; si < 64; ++si) {
        const int s = sq * 64 + si;
        const float wv = wp[(size_t)s * 2304];
        #pragma unroll
        for (int j = 0; j < 8; ++j) ag[j] += wv * mub[j * 256 + s];
    }
    __shared__ float red[4][256][9];        // +1 pad: stride 9 dwords, conflict-free
    #pragma unroll
    for (int j = 0; j < 8; ++j) red[sq][c][j] = ag[j];
    __syncthreads();
    if (sq != 0) return;
    #pragma unroll
    for (int j = 0; j < 8; ++j)
        ag[j] = (red[0][c][j] + red[1][c][j]) + (red[2][c][j] + red[3][c][j]);
    // channel c: cc group = c>>5, in-group channel = c&31
    const int cc = c >> 5, cl = c & 31;
    _Float16* base = vt + (size_t)(cc * 4 + b) * SLICE_H + z * 32 + cl;
    #pragma unroll
    for (int j = 0; j < 8; ++j) base[(tap * 9 + j) * 72] = (_Float16)ag[j];
    base[(tap * 9 + 8) * 72] = (_Float16)0.f;   // OOB sentinel (each z zeros its half)
}

// ---- K3: fused BN-apply + conv-as-gather + SPADE combine, fp16-LDS-staged V ----
// Per block: 4 h-rows x 32 channels (grid 1024 = 4 blocks/CU, single pass).
// (cc,b) fp16 V slice staged via 12 width-16 global_load_lds chunks; gathers are
// ds_read_b128 (8 fp16 ch/tap); dual 9-read g/e windows pinned by sched_barrier.
// 2-stage f-pipeline over 8 static units (4 hh x 2 cb): fA serves cb=0, fB cb=1;
// each unit's windows are followed by the NEXT unit's 8 fp loads, THEN the
// epilogue stores. vmcnt retires in issue order, so the next epilogue's wait for
// its f-values no longer drains the previous epilogue's nt-stores to HBM (the
// r11 within-iteration hoist left stores older than loads -> full store-drain
// per row; this cross-unit pipeline is the fix). All f indexing static.
__global__ void __launch_bounds__(256, 4) k_main(
    const float* __restrict__ fp, const unsigned char* __restrict__ lab,
    const char* __restrict__ vt, const float4* __restrict__ T,
    float* __restrict__ out) {
    const int h0 = blockIdx.x * 4, cc = blockIdx.y, b = blockIdx.z;
    __shared__ __align__(16) char vbuf[SLICE_B];   // [81 rows][144 B]
    __shared__ int labs[6][132];
    const int t = threadIdx.x;
    const int lane = t & 63;
    const int wid = __builtin_amdgcn_readfirstlane(t >> 6);

    // stage the (cc,b) slice: 12 x 1024 B chunks (width 16), round-robin on waves
    {
        const char* slice = vt + (size_t)(cc * 4 + b) * SLICE_B;
        for (int r = wid; r < 12; r += 4) {
            __builtin_amdgcn_global_load_lds(
                (const __attribute__((address_space(1))) void*)(slice + r * 1024 + lane * 16),
                (__attribute__((address_space(3))) void*)(vbuf + r * 1024), 16, 0, 0);
        }
    }
    for (int idx = t; idx < 6 * 132; idx += 256) {
        const int r = idx / 132, col = idx % 132 - 1;
        const int hh = h0 - 1 + r;
        int v = 8;                        // OOB sentinel -> zero row
        if (hh >= 0 && hh < Hh && col >= 0 && col < Ww)
            v = lab[((size_t)b << 14) + (hh << 7) + col];
        labs[r][idx % 132] = v;
    }

    const int w = t & 127;
    const int cs = __builtin_amdgcn_readfirstlane(t >> 7);  // 16-ch half, SGPR-forced
    const int cbase = cc * 32 + cs * 16;
    const float4* Tw = T + cbase;          // wave-uniform -> scalar loads, no LDS
    const size_t io0 = ((size_t)(b * Cc + cbase) << 14) + (h0 << 7) + w;
    const float* fpp = fp + io0;
    float* outp = out + io0;

    // prologue f-loads for unit 0 land under the staging drain of the barrier
    float fA[8], fB[8];
    #pragma unroll
    for (int i = 0; i < 8; ++i)
        fA[i] = __builtin_nontemporal_load(fpp + (size_t)i * HWp);
    __syncthreads();

    #pragma unroll
    for (int hh = 0; hh < 4; ++hh) {
        int vb0[9];
        #pragma unroll
        for (int tap = 0; tap < 9; ++tap) {
            const int j = labs[hh + tap / 3][w + tap % 3];
            vb0[tap] = (tap * 9 + j) * VROW + cs * 32;
        }
        const float* fprow = fpp + (hh << 7);
        float* outrow = outp + (hh << 7);

        // ---- unit (hh, cb=0): consumes fA, prefetches fB (ch 8..15, same row) ----
        {
            h8 vg[9];
            #pragma unroll
            for (int tap = 0; tap < 9; ++tap)
                vg[tap] = *(const h8*)(vbuf + vb0[tap]);
            __builtin_amdgcn_sched_barrier(0);
            h8 ve[9];
            #pragma unroll
            for (int tap = 0; tap < 9; ++tap)
                ve[tap] = *(const h8*)(vbuf + vb0[tap] + 64);
            #pragma unroll
            for (int i = 0; i < 8; ++i)
                fB[i] = __builtin_nontemporal_load(fprow + (size_t)(8 + i) * HWp);
            __builtin_amdgcn_sched_barrier(0);
            h8 gab = (vg[0] + vg[1]) + (vg[2] + vg[3]);
            h8 gcd = (vg[4] + vg[5]) + (vg[6] + vg[7]);
            h8 g8 = vg[8];
            h8 eab = (ve[0] + ve[1]) + (ve[2] + ve[3]);
            h8 ecd = (ve[4] + ve[5]) + (ve[6] + ve[7]);
            h8 e8 = ve[8];
            #pragma unroll
            for (int i = 0; i < 8; ++i) {
                const float4 tv = Tw[i];           // scalar (K$) load, uniform
                const float g = ((float)gab[i] + (float)gcd[i]) + (float)g8[i];
                const float e = ((float)eab[i] + (float)ecd[i]) + (float)e8[i];
                const float nf = fmaf(fA[i], tv.x, tv.y);
                __builtin_nontemporal_store(fmaf(nf, tv.z + g, tv.w + e),
                                            outrow + (size_t)i * HWp);
            }
        }
        // ---- unit (hh, cb=1): consumes fB, prefetches fA (ch 0..7, next row) ----
        {
            h8 vg[9];
            #pragma unroll
            for (int tap = 0; tap < 9; ++tap)
                vg[tap] = *(const h8*)(vbuf + vb0[tap] + 16);
            __builtin_amdgcn_sched_barrier(0);
            h8 ve[9];
            #pragma unroll
            for (int tap = 0; tap < 9; ++tap)
                ve[tap] = *(const h8*)(vbuf + vb0[tap] + 80);
            if (hh < 3) {
                #pragma unroll
                for (int i = 0; i < 8; ++i)
                    fA[i] = __builtin_nontemporal_load(fprow + 128 + (size_t)i * HWp);
            }
            __builtin_amdgcn_sched_barrier(0);
            h8 gab = (vg[0] + vg[1]) + (vg[2] + vg[3]);
            h8 gcd = (vg[4] + vg[5]) + (vg[6] + vg[7]);
            h8 g8 = vg[8];
            h8 eab = (ve[0] + ve[1]) + (ve[2] + ve[3]);
            h8 ecd = (ve[4] + ve[5]) + (ve[6] + ve[7]);
            h8 e8 = ve[8];
            #pragma unroll
            for (int i = 0; i < 8; ++i) {
                const float4 tv = Tw[8 + i];       // scalar (K$) load, uniform
                const float g = ((float)gab[i] + (float)gcd[i]) + (float)g8[i];
                const float e = ((float)eab[i] + (float)ecd[i]) + (float)e8[i];
                const float nf = fmaf(fB[i], tv.x, tv.y);
                __builtin_nontemporal_store(fmaf(nf, tv.z + g, tv.w + e),
                                            outrow + (size_t)(8 + i) * HWp);
            }
        }
    }
}

extern "C" void kernel_launch(void* const* d_in, const int* in_sizes, int n_in,
                              void* d_out, int out_size, void* d_ws, size_t ws_size,
                              hipStream_t stream) {
    const float* fp      = (const float*)d_in[0];
    const float* sg      = (const float*)d_in[1];
    const float* style   = (const float*)d_in[2];
    const int*   mask    = (const int*)d_in[3];
    const float* bn_g    = (const float*)d_in[4];
    const float* bn_b    = (const float*)d_in[5];
    const float* W_mu    = (const float*)d_in[6];
    const float* b_mu    = (const float*)d_in[7];
    const float* W_gam   = (const float*)d_in[8];
    const float* b_gam   = (const float*)d_in[9];
    const float* W_bet   = (const float*)d_in[10];
    const float* b_bet   = (const float*)d_in[11];
    float* out = (float*)d_out;

    char* ws = (char*)d_ws;
    float*         ws_f  = (float*)ws;
    unsigned char* labp  = (unsigned char*)(ws + WS_LAB);
    float*         mup   = (float*)(ws + WS_MU);
    float*         wtg   = (float*)(ws + WS_WTG);
    float*         wtb   = (float*)(ws + WS_WTB);
    _Float16*      vtp   = (_Float16*)(ws + WS_VT);

    k_prep<<<2464, 256, 0, stream>>>(fp, sg, style, mask, W_mu, b_mu, W_gam, W_bet,
                                     ws_f, labp, mup, wtg, wtb);
    k_build<<<73, 1024, 0, stream>>>(bn_g, bn_b, b_gam, b_bet, wtg, wtb, mup, ws_f, vtp);
    k_main<<<dim3(32, 8, 4), 256, 0, stream>>>(fp, labp, (const char*)vtp,
                                               (const float4*)ws_f, out);
}

// Round 13
// 59.596 us; speedup vs baseline: 1.5557x; 1.5557x over previous
//
#include <hip/hip_runtime.h>

#define Bb 4
#define Cc 256
#define Ss 256
#define Hh 128
#define Ww 128
#define Jj 8
#define HWp 16384   // H*W
#define BN_EPS 1e-5f

// ---------------- workspace byte offsets ----------------
#define WS_PS   0          // 1024 f32 partial sums; REUSED after k_build as T[256] float4
#define WS_PQ   4096       // 1024 f32 partial sumsq
#define WS_MU   10240      // mu       4*8*256 f32 (32768 B)
#define WS_LAB  43008      // labels   4*128*128 u8 (65536 B)
#define WS_WTG  108544     // Wt_gamma 2304*256 f32 (2359296 B)
#define WS_WTB  2467840    // Wt_beta  2304*256 f32
#define WS_VT   4827136    // Vt [cc8][b4] fp16 slices of 12288 B = 393216 B

// V-row (fp16): [g 32ch*2B | e 32ch*2B | 16B pad] = 144 B. j*144B = j*36 dwords ->
// start banks {0,4,...,28}: disjoint 4-bank spans for j=0..7; j=8 aliases j=0 (2-way, free).
#define VROW 144
#define SLICE_B 12288      // 81*144 = 11664, padded to 12*1024 for width-16 staging
#define SLICE_H 6144       // halves

typedef _Float16 h8 __attribute__((ext_vector_type(8)));

// ---- K1 (merged prep): bn-partial | labels | mu | transpose, split by blockIdx ----
__global__ void k_prep(const float* __restrict__ fp, const float* __restrict__ sg,
                       const float* __restrict__ style, const int* __restrict__ mask,
                       const float* __restrict__ Wmu, const float* __restrict__ bmu,
                       const float* __restrict__ Wg, const float* __restrict__ Wb,
                       float* __restrict__ ws_f, unsigned char* __restrict__ labout,
                       float* __restrict__ muout,
                       float* __restrict__ wtg, float* __restrict__ wtb) {
    __shared__ float smem[1056];           // max: transpose tile 32*33
    const int t = threadIdx.x;
    const int blk = blockIdx.x;
    if (blk < 1024) {
        // per-(c,b) partial sums for BN stats; wave shfl-reduce, 1 barrier only
        const int c = blk >> 2, b = blk & 3;
        const float4* s4 = (const float4*)(fp + (size_t)(b * Cc + c) * HWp);
        float sum = 0.f, sq = 0.f;
        #pragma unroll
        for (int k = 0; k < 16; ++k) {
            float4 v = s4[t + k * 256];
            sum += v.x + v.y + v.z + v.w;
            sq  += v.x * v.x + v.y * v.y + v.z * v.z + v.w * v.w;
        }
        #pragma unroll
        for (int off = 32; off > 0; off >>= 1) {
            sum += __shfl_xor(sum, off);
            sq  += __shfl_xor(sq,  off);
        }
        const int lane = t & 63, wv = t >> 6;
        if (lane == 0) { smem[wv] = sum; smem[4 + wv] = sq; }
        __syncthreads();
        if (t == 0) {
            ws_f[blk]        = (smem[0] + smem[1]) + (smem[2] + smem[3]);
            ws_f[1024 + blk] = (smem[4] + smem[5]) + (smem[6] + smem[7]);
        }
    } else if (blk < 1280) {
        // labels from one-hot sg
        const int i = (blk - 1024) * 256 + t;
        const int b = i >> 14, p = i & (HWp - 1);
        const float* base = sg + (size_t)b * Jj * HWp + p;
        int l = 0;
        #pragma unroll
        for (int j = 0; j < Jj; ++j)
            if (base[(size_t)j * HWp] > 0.5f) l = j;
        labout[i] = (unsigned char)l;
    } else if (blk < 1312) {
        // per-(b,j) style FC + ReLU -> mu
        const int lb = blk - 1280;
        const int b = lb >> 3, j = lb & 7;
        const int sel = (mask[b * Jj + j] == 1) ? j : Jj;
        float* code = smem;
        code[t] = style[(size_t)(b * (Jj + 1) + sel) * Ss + t];
        __syncthreads();
        const float4* wrow = (const float4*)(Wmu + (size_t)(j * Ss + t) * Ss);
        const float4* c4 = (const float4*)code;
        float acc = bmu[j * Ss + t];
        #pragma unroll 8
        for (int s4i = 0; s4i < Ss / 4; ++s4i) {
            float4 w = wrow[s4i]; float4 cv = c4[s4i];
            acc += w.x * cv.x + w.y * cv.y + w.z * cv.z + w.w * cv.w;
        }
        muout[(size_t)lb * Ss + t] = fmaxf(acc, 0.f);
    } else {
        // LDS-tiled transpose [256][2304] -> [2304][256]
        const int local = blk - 1312;            // 0..1151
        const int z = local / 576;
        const int rem = local % 576;
        const int k0 = (rem % 72) * 32;
        const int r0 = (rem / 72) * 32;
        const float* in = z ? Wb : Wg;
        float* outp = z ? wtb : wtg;
        float (*tile)[33] = (float(*)[33])smem;
        const int tx = t & 31, ty = t >> 5;
        #pragma unroll
        for (int i2 = 0; i2 < 4; ++i2)
            tile[ty + 8 * i2][tx] = in[(size_t)(r0 + ty + 8 * i2) * 2304 + k0 + tx];
        __syncthreads();
        #pragma unroll
        for (int i2 = 0; i2 < 4; ++i2)
            outp[(size_t)(k0 + ty + 8 * i2) * 256 + r0 + tx] = tile[tx][ty + 8 * i2];
    }
}

// ---- K2: blk 0 = BN finalize -> T table; blks 1..72 = Vt build, 1024 threads ----
// s-dimension split across 4 wave-groups (sq = t>>8, SGPR-forced); mu[b][j][s] is
// wave-uniform -> scalar (s_load) path, NO LDS in the MAC loop. Partials combined
// via a padded-LDS reduce. Vt layout unchanged: fp16 [tap*9+j][g 32 | e 32]; row 8 = 0.
__global__ void k_build(const float* __restrict__ bn_g, const float* __restrict__ bn_b,
                        const float* __restrict__ bgam, const float* __restrict__ bbet,
                        const float* __restrict__ wtg, const float* __restrict__ wtb,
                        const float* __restrict__ mu, float* __restrict__ ws_f,
                        _Float16* __restrict__ vt) {
    const int t = threadIdx.x;
    if (blockIdx.x == 0) {
        if (t < 256) {
            // T[c] = (scale, shift, 1 + b_gamma, b_beta); overwrites PS region (safe:
            // each thread reads exactly floats [4t,4t+4) of PS before writing them)
            float s = 0.f, q = 0.f;
            #pragma unroll
            for (int b = 0; b < 4; ++b) { s += ws_f[t * 4 + b]; q += ws_f[1024 + t * 4 + b]; }
            float mean = s * (1.f / 65536.f);
            float var  = q * (1.f / 65536.f) - mean * mean;
            float sc = bn_g[t] * rsqrtf(var + BN_EPS);
            float sh = bn_b[t] - mean * sc;
            ((float4*)ws_f)[t] = make_float4(sc, sh, 1.f + bgam[t], bbet[t]);
        }
        return;
    }
    const int lb = blockIdx.x - 1;          // 0..71
    const int z = lb / 36;
    const int rem = lb % 36;
    const int tap = rem % 9, b = rem / 9;
    const float* Wt = z ? wtb : wtg;
    const int c = t & 255;
    const int sq = __builtin_amdgcn_readfirstlane(t >> 8);   // s-quarter, SGPR
    const float* mub = mu + (size_t)b * Jj * Ss;             // wave-uniform reads
    float ag[8] = {0,0,0,0,0,0,0,0};
    const float* wp = Wt + (size_t)tap * 256 + c;
    #pragma unroll 16
    for (int si = 0; si < 64; ++si) {
        const int s = sq * 64 + si;
        const float wv = wp[(size_t)s * 2304];
        #pragma unroll
        for (int j = 0; j < 8; ++j) ag[j] += wv * mub[j * 256 + s];
    }
    __shared__ float red[4][256][9];        // +1 pad: stride 9 dwords, conflict-free
    #pragma unroll
    for (int j = 0; j < 8; ++j) red[sq][c][j] = ag[j];
    __syncthreads();
    if (sq != 0) return;
    #pragma unroll
    for (int j = 0; j < 8; ++j)
        ag[j] = (red[0][c][j] + red[1][c][j]) + (red[2][c][j] + red[3][c][j]);
    // channel c: cc group = c>>5, in-group channel = c&31
    const int cc = c >> 5, cl = c & 31;
    _Float16* base = vt + (size_t)(cc * 4 + b) * SLICE_H + z * 32 + cl;
    #pragma unroll
    for (int j = 0; j < 8; ++j) base[(tap * 9 + j) * 72] = (_Float16)ag[j];
    base[(tap * 9 + 8) * 72] = (_Float16)0.f;   // OOB sentinel (each z zeros its half)
}

// ---- K3: fused BN-apply + conv-as-gather + SPADE combine, fp16-LDS-staged V ----
// Per block: 2 h-rows x 32 channels. (cc,b) fp16 slice (11.7 KB, g|e interleaved
// 144-B rows) staged verbatim via 12 width-16 global_load_lds chunks. Gathers are
// ds_read_b128 = 8 fp16 channels per tap; dual 9-read windows (g, e) pinned by
// sched_barrier. Tap sum: fp16 pk-adds for tree levels 1-2 (9->3), f32 finish.
// T table read via wave-uniform SCALAR loads; f-loads hoisted above the windows.
// launch_bounds(256,4): 65-128 VGPR band holds the dual window w/o spill.
// [r12 post-mortem: deeper cross-unit pipelining (4hh x 2cb, fA/fB 2-stage)
//  made the allocator collapse to 64 VGPR and spill (FETCH 37->89 MB, 79 us).
//  This r11 structure is the measured optimum of the family: 59.6 us total.]
__global__ void __launch_bounds__(256, 4) k_main(
    const float* __restrict__ fp, const unsigned char* __restrict__ lab,
    const char* __restrict__ vt, const float4* __restrict__ T,
    float* __restrict__ out) {
    const int h0 = blockIdx.x * 2, cc = blockIdx.y, b = blockIdx.z;
    __shared__ __align__(16) char vbuf[SLICE_B];   // [81 rows][144 B]
    __shared__ int labs[4][132];
    const int t = threadIdx.x;
    const int lane = t & 63;
    const int wid = __builtin_amdgcn_readfirstlane(t >> 6);

    // stage the (cc,b) slice: 12 x 1024 B chunks (width 16), round-robin on waves
    {
        const char* slice = vt + (size_t)(cc * 4 + b) * SLICE_B;
        for (int r = wid; r < 12; r += 4) {
            __builtin_amdgcn_global_load_lds(
                (const __attribute__((address_space(1))) void*)(slice + r * 1024 + lane * 16),
                (__attribute__((address_space(3))) void*)(vbuf + r * 1024), 16, 0, 0);
        }
    }
    for (int idx = t; idx < 4 * 132; idx += 256) {
        const int r = idx / 132, col = idx % 132 - 1;
        const int hh = h0 - 1 + r;
        int v = 8;                        // OOB sentinel -> zero row
        if (hh >= 0 && hh < Hh && col >= 0 && col < Ww)
            v = lab[((size_t)b << 14) + (hh << 7) + col];
        labs[r][idx % 132] = v;
    }
    __syncthreads();

    const int w = t & 127;
    const int cs = __builtin_amdgcn_readfirstlane(t >> 7);  // 16-ch half, SGPR-forced
    const int cbase = cc * 32 + cs * 16;
    const float4* Tw = T + cbase;          // wave-uniform -> scalar loads, no LDS

    for (int hh = 0; hh < 2; ++hh) {
        int vb0[9];
        #pragma unroll
        for (int tap = 0; tap < 9; ++tap) {
            const int j = labs[hh + tap / 3][w + tap % 3];
            vb0[tap] = (tap * 9 + j) * VROW + cs * 32;
        }
        const size_t io = ((size_t)(b * Cc + cbase) << 14) + ((h0 + hh) << 7) + w;
        const float* fpp = fp + io;
        float* outp = out + io;
        // ---- issue ALL fp loads for this h-row up front ----
        float f[16];
        #pragma unroll
        for (int lc = 0; lc < 16; ++lc)
            f[lc] = __builtin_nontemporal_load(fpp + (size_t)lc * HWp);
        __builtin_amdgcn_sched_barrier(0);   // loads stay above the LDS windows
        #pragma unroll
        for (int cb = 0; cb < 2; ++cb) {
            // ---- gamma window: 9 x ds_read_b128 (8 fp16 channels each) ----
            h8 vg[9];
            #pragma unroll
            for (int tap = 0; tap < 9; ++tap)
                vg[tap] = *(const h8*)(vbuf + vb0[tap] + cb * 16);
            __builtin_amdgcn_sched_barrier(0);
            // ---- beta window issues while gamma partials retire ----
            h8 ve[9];
            #pragma unroll
            for (int tap = 0; tap < 9; ++tap)
                ve[tap] = *(const h8*)(vbuf + vb0[tap] + 64 + cb * 16);
            // fp16 tree levels 1-2 (frees vg), f32 finish in the epilogue
            h8 gab = (vg[0] + vg[1]) + (vg[2] + vg[3]);
            h8 gcd = (vg[4] + vg[5]) + (vg[6] + vg[7]);
            h8 g8 = vg[8];
            __builtin_amdgcn_sched_barrier(0);
            h8 eab = (ve[0] + ve[1]) + (ve[2] + ve[3]);
            h8 ecd = (ve[4] + ve[5]) + (ve[6] + ve[7]);
            h8 e8 = ve[8];
            #pragma unroll
            for (int i = 0; i < 8; ++i) {
                const int lc = cb * 8 + i;
                const float4 tv = Tw[lc];          // scalar (K$) load, uniform
                const float g = ((float)gab[i] + (float)gcd[i]) + (float)g8[i];
                const float e = ((float)eab[i] + (float)ecd[i]) + (float)e8[i];
                const float nf = fmaf(f[lc], tv.x, tv.y);
                const float res = fmaf(nf, tv.z + g, tv.w + e);
                __builtin_nontemporal_store(res, outp + (size_t)lc * HWp);
            }
        }
    }
}

extern "C" void kernel_launch(void* const* d_in, const int* in_sizes, int n_in,
                              void* d_out, int out_size, void* d_ws, size_t ws_size,
                              hipStream_t stream) {
    const float* fp      = (const float*)d_in[0];
    const float* sg      = (const float*)d_in[1];
    const float* style   = (const float*)d_in[2];
    const int*   mask    = (const int*)d_in[3];
    const float* bn_g    = (const float*)d_in[4];
    const float* bn_b    = (const float*)d_in[5];
    const float* W_mu    = (const float*)d_in[6];
    const float* b_mu    = (const float*)d_in[7];
    const float* W_gam   = (const float*)d_in[8];
    const float* b_gam   = (const float*)d_in[9];
    const float* W_bet   = (const float*)d_in[10];
    const float* b_bet   = (const float*)d_in[11];
    float* out = (float*)d_out;

    char* ws = (char*)d_ws;
    float*         ws_f  = (float*)ws;
    unsigned char* labp  = (unsigned char*)(ws + WS_LAB);
    float*         mup   = (float*)(ws + WS_MU);
    float*         wtg   = (float*)(ws + WS_WTG);
    float*         wtb   = (float*)(ws + WS_WTB);
    _Float16*      vtp   = (_Float16*)(ws + WS_VT);

    k_prep<<<2464, 256, 0, stream>>>(fp, sg, style, mask, W_mu, b_mu, W_gam, W_bet,
                                     ws_f, labp, mup, wtg, wtb);
    k_build<<<73, 1024, 0, stream>>>(bn_g, bn_b, b_gam, b_bet, wtg, wtb, mup, ws_f, vtp);
    k_main<<<dim3(64, 8, 4), 256, 0, stream>>>(fp, labp, (const char*)vtp,
                                               (const float4*)ws_f, out);
}